// Round 1
// baseline (1033.204 us; speedup 1.0000x reference)
//
#include <hip/hip_runtime.h>
#include <math.h>

#define K 128
#define V 50257
#define D 128
#define H 128
#define B 256
#define T 1024
#define NSB 256
#define WPB 197   // 256*197 = 50432 >= V

__global__ void k_transA(const float* __restrict__ trans_w, const float* __restrict__ trans_b,
                         const float* __restrict__ trans_q, float* __restrict__ A_out) {
  __shared__ __align__(16) float qs[H];
  __shared__ float red[2];
  int i = blockIdx.x;
  int j = threadIdx.x;
  qs[j] = trans_q[j];
  __syncthreads();
  const float* wrow = trans_w + (size_t)(i * K + j) * H;
  float acc = 0.f;
#pragma unroll
  for (int h = 0; h < H; h += 4) {
    float4 w4 = *(const float4*)(wrow + h);
    float4 q4 = *(const float4*)(qs + h);
    acc += w4.x * q4.x + w4.y * q4.y + w4.z * q4.z + w4.w * q4.w;
  }
  float logit = acc + trans_b[i * K + j];
  int wid = j >> 6;
  float m = logit;
  for (int o = 32; o; o >>= 1) m = fmaxf(m, __shfl_xor(m, o, 64));
  if ((j & 63) == 0) red[wid] = m;
  __syncthreads();
  m = fmaxf(red[0], red[1]);
  __syncthreads();
  float e = __expf(logit - m);
  float s = e;
  for (int o = 32; o; o >>= 1) s += __shfl_xor(s, o, 64);
  if ((j & 63) == 0) red[wid] = s;
  __syncthreads();
  s = red[0] + red[1];
  A_out[i * K + j] = e / s;   // exp(log_softmax) = A in real space
}

__global__ void k_logpi(const float* __restrict__ x, float* __restrict__ lp) {
  int j = threadIdx.x;
  __shared__ float red[2];
  float v = x[j];
  int wid = j >> 6;
  float m = v;
  for (int o = 32; o; o >>= 1) m = fmaxf(m, __shfl_xor(m, o, 64));
  if ((j & 63) == 0) red[wid] = m;
  __syncthreads();
  m = fmaxf(red[0], red[1]);
  __syncthreads();
  float e = __expf(v - m);
  float s = e;
  for (int o = 32; o; o >>= 1) s += __shfl_xor(s, o, 64);
  if ((j & 63) == 0) red[wid] = s;
  __syncthreads();
  s = red[0] + red[1];
  lp[j] = v - m - __logf(s);
}

// scoresT[w][k] = dot(tag[k], word[w]) + bias[w]; also per-k online (max,sumexp) partials
__global__ void k_scores(const float* __restrict__ tag_w, const float* __restrict__ word_w,
                         const float* __restrict__ word_b, float* __restrict__ scoresT,
                         float* __restrict__ kmaxP, float* __restrict__ ksumP) {
  __shared__ __align__(16) float wbuf[8][D];
  __shared__ float part[8][K];
  int tid = threadIdx.x;
  int k = tid & 127, h = tid >> 7;
  float4 tg[16];
  const float* trow = tag_w + k * D + h * 64;
#pragma unroll
  for (int q = 0; q < 16; q++) tg[q] = *(const float4*)(trow + 4 * q);
  int w0 = blockIdx.x * WPB;
  int wend = min(w0 + WPB, V);
  float kmax = -1e30f, ksum = 0.f;
  for (int wb = w0; wb < wend; wb += 8) {
    int wsel = tid >> 5;
    int dsel = (tid & 31) * 4;
    int wg = min(wb + wsel, V - 1);
    *(float4*)&wbuf[wsel][dsel] = *(const float4*)(word_w + (size_t)wg * D + dsel);
    __syncthreads();
    int nw = min(8, wend - wb);
    float acc[8];
#pragma unroll
    for (int q = 0; q < 8; q++) acc[q] = 0.f;
#pragma unroll
    for (int q = 0; q < 8; q++) {
      if (q < nw) {
        const float* wr = &wbuf[q][h * 64];
        float a = 0.f;
#pragma unroll
        for (int ii = 0; ii < 16; ii++) {
          float4 w4 = *(const float4*)(wr + 4 * ii);
          a += tg[ii].x * w4.x + tg[ii].y * w4.y + tg[ii].z * w4.z + tg[ii].w * w4.w;
        }
        acc[q] = a;
      }
    }
    if (h == 1) {
#pragma unroll
      for (int q = 0; q < 8; q++) part[q][k] = acc[q];
    }
    __syncthreads();
    if (h == 0) {
      for (int q = 0; q < nw; q++) {
        int w = wb + q;
        float s = acc[q] + part[q][k] + word_b[w];
        scoresT[(size_t)w * K + k] = s;
        if (s > kmax) { ksum *= __expf(kmax - s); kmax = s; }
        ksum += __expf(s - kmax);
      }
    }
    __syncthreads();
  }
  if (h == 0) {
    kmaxP[blockIdx.x * K + k] = kmax;
    ksumP[blockIdx.x * K + k] = ksum;
  }
}

__global__ void k_lse(const float* __restrict__ kmaxP, const float* __restrict__ ksumP,
                      float* __restrict__ lse) {
  int k = threadIdx.x;
  float m = -1e30f;
  for (int b = 0; b < NSB; b++) m = fmaxf(m, kmaxP[b * K + k]);
  float s = 0.f;
  for (int b = 0; b < NSB; b++) s += ksumP[b * K + k] * __expf(kmaxP[b * K + k] - m);
  lse[k] = m + __logf(s);
}

__global__ void __launch_bounds__(256) k_forward(
    const int* __restrict__ emis, const float* __restrict__ scoresT,
    const float* __restrict__ A, const float* __restrict__ log_pi,
    const float* __restrict__ lse, float* __restrict__ sll) {
  __shared__ __align__(16) float ps[K];
  __shared__ float part[K];
  __shared__ float red[2];
  __shared__ int es[T];
  int b = blockIdx.x;
  int tid = threadIdx.x;
  int j = tid & 127, h = tid >> 7;
  for (int t = tid; t < T; t += 256) es[t] = emis[b * T + t];
  float Areg[64];
#pragma unroll
  for (int ii = 0; ii < 64; ii++) Areg[ii] = A[(64 * h + ii) * K + j];
  float lsej = lse[j];
  float lpj = log_pi[j];
  __syncthreads();
  int w0 = es[0];
  float a = lpj + scoresT[(size_t)w0 * K + j] - lsej;  // alpha_0 (valid tid<128)
  float nsc = 0.f;
  if (tid < 128) nsc = scoresT[(size_t)es[1] * K + j];
  for (int t = 1; t < T; t++) {
    float csc = nsc;
    if (tid < 128 && t + 1 < T) nsc = scoresT[(size_t)es[t + 1] * K + j];
    // current max over alpha (waves 0,1 hold alpha)
    float mm = a;
#pragma unroll
    for (int o = 32; o; o >>= 1) mm = fmaxf(mm, __shfl_xor(mm, o, 64));
    if (tid == 0) red[0] = mm;
    if (tid == 64) red[1] = mm;
    __syncthreads();
    float m = fmaxf(red[0], red[1]);
    if (tid < 128) ps[j] = __expf(a - m);
    __syncthreads();
    // matvec: new[j] = sum_i p[i] * A[i][j]; thread covers i in [64h,64h+64)
    float a0 = 0, a1 = 0, a2 = 0, a3 = 0;
    const float* pp = &ps[64 * h];
#pragma unroll
    for (int ii = 0; ii < 16; ii++) {
      float4 p4 = *(const float4*)(pp + 4 * ii);
      a0 += p4.x * Areg[4 * ii + 0];
      a1 += p4.y * Areg[4 * ii + 1];
      a2 += p4.z * Areg[4 * ii + 2];
      a3 += p4.w * Areg[4 * ii + 3];
    }
    float acc = (a0 + a1) + (a2 + a3);
    if (h == 1) part[j] = acc;
    __syncthreads();
    if (h == 0) {
      float tot = acc + part[j];
      a = m + __logf(tot) + csc - lsej;
    }
  }
  __syncthreads();
  // final logsumexp over alpha
  float mm = (tid < 128) ? a : -1e30f;
#pragma unroll
  for (int o = 32; o; o >>= 1) mm = fmaxf(mm, __shfl_xor(mm, o, 64));
  if (tid == 0) red[0] = mm;
  if (tid == 64) red[1] = mm;
  __syncthreads();
  float m2 = fmaxf(red[0], red[1]);
  float e = (tid < 128) ? __expf(a - m2) : 0.f;
#pragma unroll
  for (int o = 32; o; o >>= 1) e += __shfl_xor(e, o, 64);
  __syncthreads();
  if (tid == 0) red[0] = e;
  if (tid == 64) red[1] = e;
  __syncthreads();
  if (tid == 0) sll[b] = m2 + __logf(red[0] + red[1]);
}

__global__ void k_loss(const float* __restrict__ sll, float* __restrict__ out) {
  int tid = threadIdx.x;
  __shared__ float red[4];
  float v = sll[tid];
#pragma unroll
  for (int o = 32; o; o >>= 1) v += __shfl_xor(v, o, 64);
  if ((tid & 63) == 0) red[tid >> 6] = v;
  __syncthreads();
  if (tid == 0) out[0] = -(red[0] + red[1] + red[2] + red[3]) / (float)B;
}

extern "C" void kernel_launch(void* const* d_in, const int* in_sizes, int n_in,
                              void* d_out, int out_size, void* d_ws, size_t ws_size,
                              hipStream_t stream) {
  const int*   emis   = (const int*)d_in[0];
  const float* initl  = (const float*)d_in[1];
  const float* tagw   = (const float*)d_in[2];
  const float* wordw  = (const float*)d_in[3];
  const float* wordb  = (const float*)d_in[4];
  const float* transw = (const float*)d_in[5];
  const float* transb = (const float*)d_in[6];
  const float* transq = (const float*)d_in[7];
  float* ws = (float*)d_ws;
  size_t off = 0;
  float* scoresT = ws + off; off += (size_t)V * K;
  float* Amat    = ws + off; off += (size_t)K * K;
  float* logpi   = ws + off; off += K;
  float* lse     = ws + off; off += K;
  float* kmaxP   = ws + off; off += (size_t)NSB * K;
  float* ksumP   = ws + off; off += (size_t)NSB * K;
  float* sll     = ws + off; off += B;
  float* out = (float*)d_out;

  hipLaunchKernelGGL(k_transA, dim3(K), dim3(K), 0, stream, transw, transb, transq, Amat);
  hipLaunchKernelGGL(k_logpi, dim3(1), dim3(K), 0, stream, initl, logpi);
  hipLaunchKernelGGL(k_scores, dim3(NSB), dim3(256), 0, stream, tagw, wordw, wordb, scoresT, kmaxP, ksumP);
  hipLaunchKernelGGL(k_lse, dim3(1), dim3(K), 0, stream, kmaxP, ksumP, lse);
  hipLaunchKernelGGL(k_forward, dim3(B), dim3(256), 0, stream, emis, scoresT, Amat, logpi, lse, sll);
  hipLaunchKernelGGL(k_loss, dim3(1), dim3(256), 0, stream, sll, out);
}

// Round 2
// 929.247 us; speedup vs baseline: 1.1119x; 1.1119x over previous
//
#include <hip/hip_runtime.h>
#include <math.h>

#define K 128
#define V 50257
#define D 128
#define H 128
#define B 256
#define T 1024
#define NLB 256
#define WPB 197   // 256*197 = 50432 >= V

// ---- DPP wave reduces (result valid in lane 63) ----
__device__ __forceinline__ float wave_max63(float x) {
  int xi;
#define MSTEP(ctrl, rm, bm)                                                          \
  xi = __builtin_amdgcn_update_dpp(__float_as_int(x), __float_as_int(x), ctrl, rm,   \
                                   bm, false);                                       \
  x = fmaxf(x, __int_as_float(xi));
  MSTEP(0x111, 0xf, 0xf)  // row_shr:1
  MSTEP(0x112, 0xf, 0xf)  // row_shr:2
  MSTEP(0x114, 0xf, 0xe)  // row_shr:4
  MSTEP(0x118, 0xf, 0xc)  // row_shr:8
  MSTEP(0x142, 0xa, 0xf)  // row_bcast:15
  MSTEP(0x143, 0xc, 0xf)  // row_bcast:31
#undef MSTEP
  return x;
}
__device__ __forceinline__ float wave_sum63(float x) {
  int xi;
#define SSTEP(ctrl, rm, bm)                                                          \
  xi = __builtin_amdgcn_update_dpp(0, __float_as_int(x), ctrl, rm, bm, true);        \
  x = x + __int_as_float(xi);
  SSTEP(0x111, 0xf, 0xf)
  SSTEP(0x112, 0xf, 0xf)
  SSTEP(0x114, 0xf, 0xe)
  SSTEP(0x118, 0xf, 0xc)
  SSTEP(0x142, 0xa, 0xf)
  SSTEP(0x143, 0xc, 0xf)
#undef SSTEP
  return x;
}

__global__ void k_transA(const float* __restrict__ trans_w, const float* __restrict__ trans_b,
                         const float* __restrict__ trans_q, float* __restrict__ A_out) {
  __shared__ __align__(16) float qs[H];
  __shared__ float red[2];
  int i = blockIdx.x;
  int j = threadIdx.x;
  qs[j] = trans_q[j];
  __syncthreads();
  const float* wrow = trans_w + (size_t)(i * K + j) * H;
  float acc = 0.f;
#pragma unroll
  for (int h = 0; h < H; h += 4) {
    float4 w4 = *(const float4*)(wrow + h);
    float4 q4 = *(const float4*)(qs + h);
    acc += w4.x * q4.x + w4.y * q4.y + w4.z * q4.z + w4.w * q4.w;
  }
  float logit = acc + trans_b[i * K + j];
  int wid = j >> 6;
  float m = logit;
  for (int o = 32; o; o >>= 1) m = fmaxf(m, __shfl_xor(m, o, 64));
  if ((j & 63) == 0) red[wid] = m;
  __syncthreads();
  m = fmaxf(red[0], red[1]);
  __syncthreads();
  float e = __expf(logit - m);
  float s = e;
  for (int o = 32; o; o >>= 1) s += __shfl_xor(s, o, 64);
  if ((j & 63) == 0) red[wid] = s;
  __syncthreads();
  s = red[0] + red[1];
  A_out[i * K + j] = e / s;  // transition probs in real space
}

__global__ void k_pi(const float* __restrict__ x, float* __restrict__ pi) {
  int j = threadIdx.x;
  __shared__ float red[2];
  float v = x[j];
  int wid = j >> 6;
  float m = v;
  for (int o = 32; o; o >>= 1) m = fmaxf(m, __shfl_xor(m, o, 64));
  if ((j & 63) == 0) red[wid] = m;
  __syncthreads();
  m = fmaxf(red[0], red[1]);
  __syncthreads();
  float e = __expf(v - m);
  float s = e;
  for (int o = 32; o; o >>= 1) s += __shfl_xor(s, o, 64);
  if ((j & 63) == 0) red[wid] = s;
  __syncthreads();
  s = red[0] + red[1];
  pi[j] = e / (red[0] + red[1]);
}

// scoresT[w][k] = dot(tag[k], word[w]) + bias[w]; thread-per-word, tags in LDS
__global__ void __launch_bounds__(256) k_scores(const float* __restrict__ tag_w,
                                                const float* __restrict__ word_w,
                                                const float* __restrict__ word_b,
                                                float* __restrict__ scoresT) {
  __shared__ __align__(16) float tg[K][D];  // 64 KB
  int tid = threadIdx.x;
#pragma unroll
  for (int q = 0; q < 16; q++) {
    int f4 = q * 256 + tid;
    ((float4*)tg)[f4] = ((const float4*)tag_w)[f4];
  }
  __syncthreads();
  int w = blockIdx.x * 256 + tid;
  if (w >= V) return;
  float wb = word_b[w];
  float4 wreg[32];
#pragma unroll
  for (int c = 0; c < 32; c++) wreg[c] = *(const float4*)(word_w + (size_t)w * D + 4 * c);
  for (int k4 = 0; k4 < 32; k4++) {
    float4 out;
    float* op = (float*)&out;
#pragma unroll
    for (int kk = 0; kk < 4; kk++) {
      int k = k4 * 4 + kk;
      float a0 = 0, a1 = 0, a2 = 0, a3 = 0;
#pragma unroll
      for (int c = 0; c < 32; c++) {
        float4 t4 = *(const float4*)&tg[k][4 * c];
        a0 = fmaf(t4.x, wreg[c].x, a0);
        a1 = fmaf(t4.y, wreg[c].y, a1);
        a2 = fmaf(t4.z, wreg[c].z, a2);
        a3 = fmaf(t4.w, wreg[c].w, a3);
      }
      op[kk] = (a0 + a1) + (a2 + a3) + wb;
    }
    *(float4*)&scoresT[(size_t)w * K + 4 * k4] = out;
  }
}

// per-k online (max,sumexp) over a word slice
__global__ void __launch_bounds__(256) k_collse(const float* __restrict__ scoresT,
                                                float* __restrict__ pmax,
                                                float* __restrict__ psum) {
  int tid = threadIdx.x;
  int blk = blockIdx.x;
  int k = tid & 127, half = tid >> 7;
  int w0 = blk * WPB;
  int wend = min(w0 + WPB, V);
  float m = -1e30f, s = 0.f;
  for (int w = w0 + half; w < wend; w += 2) {
    float v = scoresT[(size_t)w * K + k];
    if (v > m) { s *= __expf(m - v); m = v; }
    s += __expf(v - m);
  }
  pmax[blk * 256 + tid] = m;
  psum[blk * 256 + tid] = s;
}

__global__ void k_lsefin(const float* __restrict__ pmax, const float* __restrict__ psum,
                         float* __restrict__ lse) {
  __shared__ float sm[2][K], ss[2][K];
  int tid = threadIdx.x;
  int k = tid & 127, half = tid >> 7;
  float m = -1e30f, s = 0.f;
  for (int blk = 0; blk < NLB; blk++) {
    float pm = pmax[blk * 256 + half * 128 + k];
    float pv = psum[blk * 256 + half * 128 + k];
    float nm = fmaxf(m, pm);
    s = s * __expf(m - nm) + pv * __expf(pm - nm);
    m = nm;
  }
  sm[half][k] = m;
  ss[half][k] = s;
  __syncthreads();
  if (tid < K) {
    float nm = fmaxf(sm[0][tid], sm[1][tid]);
    float st = ss[0][tid] * __expf(sm[0][tid] - nm) + ss[1][tid] * __expf(sm[1][tid] - nm);
    lse[tid] = nm + __logf(st);
  }
}

// in-place: scoresT[w][k] -> exp(score - lse[k]); bmaxexp[w] = row max
__global__ void __launch_bounds__(256) k_expb(float* __restrict__ scoresT,
                                              const float* __restrict__ lse,
                                              float* __restrict__ bmaxexp) {
  __shared__ __align__(16) float ls[K];
  int tid = threadIdx.x;
  if (tid < K) ls[tid] = lse[tid];
  __syncthreads();
  int w = blockIdx.x * 256 + tid;
  if (w >= V) return;
  float* row = scoresT + (size_t)w * K;
  float mx = 0.f;
#pragma unroll
  for (int c = 0; c < 32; c++) {
    float4 s4 = *(float4*)&row[4 * c];
    float4 l4 = *(const float4*)&ls[4 * c];
    float4 e;
    e.x = __expf(s4.x - l4.x);
    e.y = __expf(s4.y - l4.y);
    e.z = __expf(s4.z - l4.z);
    e.w = __expf(s4.w - l4.w);
    mx = fmaxf(mx, fmaxf(fmaxf(e.x, e.y), fmaxf(e.z, e.w)));
    *(float4*)&row[4 * c] = e;
  }
  bmaxexp[w] = mx;
}

// real-space forward recurrence with lazy rescaling
__global__ void __launch_bounds__(256) k_forward(
    const int* __restrict__ emis, const float* __restrict__ expb,
    const float* __restrict__ bmaxexp, const float* __restrict__ A,
    const float* __restrict__ pi, float* __restrict__ sll) {
  __shared__ __align__(16) float ps[K];
  __shared__ float part[2][K];
  __shared__ float zpb[2][2];
  __shared__ float spb[2];
  __shared__ int es[T];
  int b = blockIdx.x;
  int tid = threadIdx.x;
  int lane = tid & 63;
  int wv = tid >> 6;
  int h = wv >> 1;                  // i-range half
  int j = ((wv & 1) << 6) | lane;   // state column
  for (int t = tid; t < T; t += 256) es[t] = emis[b * T + t];
  float Areg[64];
#pragma unroll
  for (int ii = 0; ii < 64; ii++) Areg[ii] = A[(64 * h + ii) * K + j];
  __syncthreads();  // es ready
  int w0 = es[0], w1 = es[1], w2 = es[2];
  float p1 = pi[j] * expb[(size_t)w0 * K + j];
  float bw_cur = expb[(size_t)w1 * K + j];
  float bmx_cur = bmaxexp[w1];
  float bw_nxt = expb[(size_t)w2 * K + j];
  float bmx_nxt = bmaxexp[w2];
  if (h == 0) {
    ps[j] = p1;
  } else {
    float zm = wave_max63(p1);
    if (lane == 63) zpb[0][wv & 1] = zm;
  }
  float Cacc = 0.f;
  __syncthreads();
  float pn = p1;
  for (int t = 1; t < T; t++) {
    // ---- stage 1: prefetch + scale + matvec partial ----
    int tf = (t + 2 < T) ? t + 2 : T - 1;
    int wf = es[tf];
    float bwf = expb[(size_t)wf * K + j];
    float bmf = bmaxexp[wf];
    float z = fmaxf(zpb[(t - 1) & 1][0], zpb[(t - 1) & 1][1]);  // = max_j p_t[j], exact
    float zb = z * bmx_cur;
    float r = 1.0f / zb;
    Cacc += __logf(zb);  // off critical path
    float a0 = 0, a1 = 0, a2 = 0, a3 = 0;
    const float* pp = &ps[64 * h];
#pragma unroll
    for (int ii = 0; ii < 16; ii++) {
      float4 p4 = *(const float4*)(pp + 4 * ii);
      a0 = fmaf(p4.x, Areg[4 * ii + 0], a0);
      a1 = fmaf(p4.y, Areg[4 * ii + 1], a1);
      a2 = fmaf(p4.z, Areg[4 * ii + 2], a2);
      a3 = fmaf(p4.w, Areg[4 * ii + 3], a3);
    }
    part[h][j] = (a0 + a1) + (a2 + a3);
    __syncthreads();  // bX
    // ---- stage 2: combine + rescale + publish ----
    float q = (part[0][j] + part[1][j]) * bw_cur;
    pn = q * r;
    if (h == 0) {
      ps[j] = pn;
    } else {
      float zm = wave_max63(pn);
      if (lane == 63) zpb[t & 1][wv & 1] = zm;
    }
    __syncthreads();  // bY
    bw_cur = bw_nxt;  bmx_cur = bmx_nxt;
    bw_nxt = bwf;     bmx_nxt = bmf;
  }
  // seq_ll = Cacc + log(sum_j p_T[j])
  if (h == 0) {
    float s = wave_sum63(pn);
    if (lane == 63) spb[wv & 1] = s;
  }
  __syncthreads();
  if (tid == 0) sll[b] = Cacc + __logf(spb[0] + spb[1]);
}

__global__ void k_loss(const float* __restrict__ sll, float* __restrict__ out) {
  int tid = threadIdx.x;
  __shared__ float red[4];
  float v = sll[tid];
#pragma unroll
  for (int o = 32; o; o >>= 1) v += __shfl_xor(v, o, 64);
  if ((tid & 63) == 0) red[tid >> 6] = v;
  __syncthreads();
  if (tid == 0) out[0] = -(red[0] + red[1] + red[2] + red[3]) / (float)B;
}

extern "C" void kernel_launch(void* const* d_in, const int* in_sizes, int n_in,
                              void* d_out, int out_size, void* d_ws, size_t ws_size,
                              hipStream_t stream) {
  const int*   emis   = (const int*)d_in[0];
  const float* initl  = (const float*)d_in[1];
  const float* tagw   = (const float*)d_in[2];
  const float* wordw  = (const float*)d_in[3];
  const float* wordb  = (const float*)d_in[4];
  const float* transw = (const float*)d_in[5];
  const float* transb = (const float*)d_in[6];
  const float* transq = (const float*)d_in[7];
  float* ws = (float*)d_ws;
  size_t off = 0;
  float* scoresT = ws + off; off += (size_t)V * K;   // becomes expb in-place
  float* Amat    = ws + off; off += (size_t)K * K;
  float* pivec   = ws + off; off += K;
  float* lse     = ws + off; off += K;
  float* pmax    = ws + off; off += (size_t)NLB * 256;
  float* psum    = ws + off; off += (size_t)NLB * 256;
  float* bmaxexp = ws + off; off += (size_t)V + 64;
  float* sll     = ws + off; off += B;
  float* out = (float*)d_out;

  hipLaunchKernelGGL(k_transA, dim3(K), dim3(K), 0, stream, transw, transb, transq, Amat);
  hipLaunchKernelGGL(k_pi, dim3(1), dim3(K), 0, stream, initl, pivec);
  hipLaunchKernelGGL(k_scores, dim3((V + 255) / 256), dim3(256), 0, stream, tagw, wordw, wordb, scoresT);
  hipLaunchKernelGGL(k_collse, dim3(NLB), dim3(256), 0, stream, scoresT, pmax, psum);
  hipLaunchKernelGGL(k_lsefin, dim3(1), dim3(256), 0, stream, pmax, psum, lse);
  hipLaunchKernelGGL(k_expb, dim3((V + 255) / 256), dim3(256), 0, stream, scoresT, lse, bmaxexp);
  hipLaunchKernelGGL(k_forward, dim3(B), dim3(256), 0, stream, emis, scoresT, bmaxexp, Amat, pivec, sll);
  hipLaunchKernelGGL(k_loss, dim3(1), dim3(256), 0, stream, sll, out);
}